// Round 1
// baseline (1713.735 us; speedup 1.0000x reference)
//
#include <hip/hip_runtime.h>

#define NB 32              // batch
#define S  512             // H == W == scan length == line length
#define HW (512 * 512)

__device__ __forceinline__ float fsig(float v) {
    return __builtin_amdgcn_rcpf(1.0f + __expf(-v));
}
__device__ __forceinline__ float ftanh(float v) {
    // tanh(x) = 1 - 2/(1+exp(2x)); saturates correctly at +-inf
    return fmaf(-2.0f, __builtin_amdgcn_rcpf(1.0f + __expf(2.0f * v)), 1.0f);
}

// One block per (image, direction). 512 threads; thread t owns line position t
// (w for row scan, h for col scan). Scans S steps with one barrier per step.
__global__ __launch_bounds__(512) void csrn_scan(
    const float* __restrict__ x,
    const float* __restrict__ wih_r, const float* __restrict__ whh_r,
    const float* __restrict__ bih_r, const float* __restrict__ bhh_r,
    const float* __restrict__ cw_r,  const float* __restrict__ cb_r,
    const float* __restrict__ wih_c, const float* __restrict__ whh_c,
    const float* __restrict__ bih_c, const float* __restrict__ bhh_c,
    const float* __restrict__ cw_c,  const float* __restrict__ cb_c,
    const float* __restrict__ comb_w,
    float* __restrict__ out)
{
    const int  t     = threadIdx.x;
    const bool isCol = (blockIdx.x >= NB);
    const int  b     = blockIdx.x & (NB - 1);

    const float* wih = isCol ? wih_c : wih_r;
    const float* whh = isCol ? whh_c : whh_r;
    const float* bih = isCol ? bih_c : bih_r;
    const float* bhh = isCol ? bhh_c : bhh_r;
    const float* cw  = isCol ? cw_c  : cw_r;
    const float* cb  = isCol ? cb_c  : cb_r;

    // All weights to registers (block-uniform; compiler scalarizes where it can)
    float Wih[27], Whh[27], Cw[27], Bih[9], Bhh[9], Cb[3], Wo[9];
#pragma unroll
    for (int i = 0; i < 27; ++i) { Wih[i] = wih[i]; Whh[i] = whh[i]; Cw[i] = cw[i]; }
#pragma unroll
    for (int i = 0; i < 9; ++i) { Bih[i] = bih[i]; Bhh[i] = bhh[i]; }
#pragma unroll
    for (int i = 0; i < 3; ++i) Cb[i] = cb[i];
    const int off = isCol ? 3 : 0;   // ctx_left uses combine_w[:, 3:6]
#pragma unroll
    for (int o = 0; o < 3; ++o)
#pragma unroll
        for (int c = 0; c < 3; ++c)
            Wo[o * 3 + c] = comb_w[o * 6 + off + c];

    // Double-buffered line of hn, with zero halo at [0] and [S+1]
    __shared__ float lds[2][S + 2][3];
    if (t < 3) {
        lds[0][0][t] = 0.f; lds[0][S + 1][t] = 0.f;
        lds[1][0][t] = 0.f; lds[1][S + 1][t] = 0.f;
    }

    // Per-thread global index of (b, c=0, step s, pos t); channel stride = HW
    int pos, stride;
    if (!isCol) { pos = b * 3 * HW + t;     stride = S; } // x[b,c,s,t]
    else        { pos = b * 3 * HW + t * S; stride = 1; } // x[b,c,t,s]

    float h0 = 0.f, h1 = 0.f, h2 = 0.f;
    float xa = x[pos], xb = x[pos + HW], xc = x[pos + 2 * HW];

    for (int s = 0; s < S; ++s) {
        const int nxt = pos + stride;
        float na = 0.f, nb = 0.f, nc = 0.f;
        if (s + 1 < S) {            // prefetch next step's input
            na = x[nxt];
            nb = x[nxt + HW];
            nc = x[nxt + 2 * HW];
        }

        // ---- GRU cell (PyTorch gate order r,z,n) ----
        float gi[9], gh[9];
#pragma unroll
        for (int j = 0; j < 9; ++j) {
            gi[j] = fmaf(Wih[j * 3 + 2], xc,
                    fmaf(Wih[j * 3 + 1], xb,
                    fmaf(Wih[j * 3 + 0], xa, Bih[j])));
            gh[j] = fmaf(Whh[j * 3 + 2], h2,
                    fmaf(Whh[j * 3 + 1], h1,
                    fmaf(Whh[j * 3 + 0], h0, Bhh[j])));
        }
        const float r0 = fsig(gi[0] + gh[0]);
        const float r1 = fsig(gi[1] + gh[1]);
        const float r2 = fsig(gi[2] + gh[2]);
        const float z0 = fsig(gi[3] + gh[3]);
        const float z1 = fsig(gi[4] + gh[4]);
        const float z2 = fsig(gi[5] + gh[5]);
        const float n0 = ftanh(fmaf(r0, gh[6], gi[6]));
        const float n1 = ftanh(fmaf(r1, gh[7], gi[7]));
        const float n2 = ftanh(fmaf(r2, gh[8], gi[8]));
        const float c0 = fmaf(z0, h0 - n0, n0);  // (1-z)*n + z*h
        const float c1 = fmaf(z1, h1 - n1, n1);
        const float c2 = fmaf(z2, h2 - n2, n2);

        // ---- exchange hn along the line ----
        const int buf = s & 1;
        lds[buf][t + 1][0] = c0;
        lds[buf][t + 1][1] = c1;
        lds[buf][t + 1][2] = c2;
        __syncthreads();

        // ---- conv1d(k=3, pad=1) + tanh -> next hidden ----
        float a0 = Cb[0], a1 = Cb[1], a2 = Cb[2];
#pragma unroll
        for (int k = 0; k < 3; ++k) {
            const float v0 = lds[buf][t + k][0];
            const float v1 = lds[buf][t + k][1];
            const float v2 = lds[buf][t + k][2];
            a0 = fmaf(Cw[0 + 0 * 3 + k], v0, fmaf(Cw[0 + 1 * 3 + k], v1, fmaf(Cw[0 + 2 * 3 + k], v2, a0)));
            a1 = fmaf(Cw[9 + 0 * 3 + k], v0, fmaf(Cw[9 + 1 * 3 + k], v1, fmaf(Cw[9 + 2 * 3 + k], v2, a1)));
            a2 = fmaf(Cw[18 + 0 * 3 + k], v0, fmaf(Cw[18 + 1 * 3 + k], v1, fmaf(Cw[18 + 2 * 3 + k], v2, a2)));
        }
        h0 = ftanh(a0); h1 = ftanh(a1); h2 = ftanh(a2);

        // ---- fold this direction's combine slice, accumulate into out ----
        unsafeAtomicAdd(&out[pos],          fmaf(Wo[2], c2, fmaf(Wo[1], c1, Wo[0] * c0)));
        unsafeAtomicAdd(&out[pos + HW],     fmaf(Wo[5], c2, fmaf(Wo[4], c1, Wo[3] * c0)));
        unsafeAtomicAdd(&out[pos + 2 * HW], fmaf(Wo[8], c2, fmaf(Wo[7], c1, Wo[6] * c0)));

        pos = nxt; xa = na; xb = nb; xc = nc;
    }
}

// out = sigmoid(out + combine_b[channel]), vectorized float4, in place
__global__ __launch_bounds__(256) void csrn_finish(
    float* __restrict__ out, const float* __restrict__ comb_b, int n4)
{
    const float b0 = comb_b[0], b1 = comb_b[1], b2 = comb_b[2];
    float4* o4 = reinterpret_cast<float4*>(out);
    for (int i = blockIdx.x * blockDim.x + threadIdx.x; i < n4;
         i += gridDim.x * blockDim.x) {
        float4 v = o4[i];
        const int o = (i >> 16) % 3;           // elem index = 4i; HW = 2^18
        const float bb = (o == 0) ? b0 : ((o == 1) ? b1 : b2);
        v.x = fsig(v.x + bb);
        v.y = fsig(v.y + bb);
        v.z = fsig(v.z + bb);
        v.w = fsig(v.w + bb);
        o4[i] = v;
    }
}

extern "C" void kernel_launch(void* const* d_in, const int* in_sizes, int n_in,
                              void* d_out, int out_size, void* d_ws, size_t ws_size,
                              hipStream_t stream)
{
    const float* x      = (const float*)d_in[0];
    const float* wih_r  = (const float*)d_in[1];
    const float* whh_r  = (const float*)d_in[2];
    const float* bih_r  = (const float*)d_in[3];
    const float* bhh_r  = (const float*)d_in[4];
    const float* cw_r   = (const float*)d_in[5];
    const float* cb_r   = (const float*)d_in[6];
    const float* wih_c  = (const float*)d_in[7];
    const float* whh_c  = (const float*)d_in[8];
    const float* bih_c  = (const float*)d_in[9];
    const float* bhh_c  = (const float*)d_in[10];
    const float* cw_c   = (const float*)d_in[11];
    const float* cb_c   = (const float*)d_in[12];
    const float* comb_w = (const float*)d_in[13];
    const float* comb_b = (const float*)d_in[14];
    float* out = (float*)d_out;

    // out accumulates two atomic contributions per element -> zero it each call
    hipMemsetAsync(d_out, 0, (size_t)out_size * sizeof(float), stream);

    // 64 blocks: [0,32) row scans, [32,64) col scans — run concurrently
    csrn_scan<<<dim3(2 * NB), dim3(S), 0, stream>>>(
        x, wih_r, whh_r, bih_r, bhh_r, cw_r, cb_r,
        wih_c, whh_c, bih_c, bhh_c, cw_c, cb_c, comb_w, out);

    const int n4 = out_size / 4;
    csrn_finish<<<dim3(4096), dim3(256), 0, stream>>>(out, comb_b, n4);
}

// Round 3
// 1009.802 us; speedup vs baseline: 1.6971x; 1.6971x over previous
//
#include <hip/hip_runtime.h>

#define NB 32              // batch
#define S  512             // H == W == scan length == line length
#define HW (512 * 512)
#define IMG (3 * HW)       // floats per image (C=3)

__device__ __forceinline__ float fsig(float v) {
    return __builtin_amdgcn_rcpf(1.0f + __expf(-v));
}
__device__ __forceinline__ float ftanh(float v) {
    // tanh(x) = 1 - 2/(1+exp(2x)); saturates correctly at +-inf
    return fmaf(-2.0f, __builtin_amdgcn_rcpf(1.0f + __expf(2.0f * v)), 1.0f);
}

// Barrier that only drains LDS ops (lgkmcnt), NOT vmcnt: global stores/atomics
// and prefetch loads stay in flight across steps. __syncthreads() would emit
// s_waitcnt vmcnt(0) and serialize every step on store completion (~7000 cyc
// stall measured in round 1).
__device__ __forceinline__ void line_barrier() {
    asm volatile("s_waitcnt lgkmcnt(0)" ::: "memory");
    __builtin_amdgcn_s_barrier();
    asm volatile("" ::: "memory");
}

// One block per (image, direction). 512 threads; thread t owns line position t.
// ATOMIC=1: both directions unsafeAtomicAdd into out (dstRow==dstCol==out).
// ATOMIC=0: row scans plain-store to dstRow (=out), col scans to dstCol (=ws).
template <int ATOMIC>
__global__ __launch_bounds__(512) void csrn_scan(
    const float* __restrict__ x,
    const float* __restrict__ wih_r, const float* __restrict__ whh_r,
    const float* __restrict__ bih_r, const float* __restrict__ bhh_r,
    const float* __restrict__ cw_r,  const float* __restrict__ cb_r,
    const float* __restrict__ wih_c, const float* __restrict__ whh_c,
    const float* __restrict__ bih_c, const float* __restrict__ bhh_c,
    const float* __restrict__ cw_c,  const float* __restrict__ cb_c,
    const float* __restrict__ comb_w,
    float* __restrict__ dstRow, float* __restrict__ dstCol)
{
    const int  t     = threadIdx.x;
    const bool isCol = (blockIdx.x >= NB);
    const int  b     = blockIdx.x & (NB - 1);

    const float* wih = isCol ? wih_c : wih_r;
    const float* whh = isCol ? whh_c : whh_r;
    const float* bih = isCol ? bih_c : bih_r;
    const float* bhh = isCol ? bhh_c : bhh_r;
    const float* cw  = isCol ? cw_c  : cw_r;
    const float* cb  = isCol ? cb_c  : cb_r;
    float* dst = isCol ? dstCol : dstRow;

    // Weights into private registers BEFORE the loop (local arrays are not
    // invalidated by the asm "memory" clobbers in line_barrier).
    float Wih[27], Whh[27], Cw[27], Bih[9], Bhh[9], Cb[3], Wo[9];
#pragma unroll
    for (int i = 0; i < 27; ++i) { Wih[i] = wih[i]; Whh[i] = whh[i]; Cw[i] = cw[i]; }
#pragma unroll
    for (int i = 0; i < 9; ++i) { Bih[i] = bih[i]; Bhh[i] = bhh[i]; }
#pragma unroll
    for (int i = 0; i < 3; ++i) Cb[i] = cb[i];
    const int off = isCol ? 3 : 0;   // ctx_left uses combine_w[:, 3:6]
#pragma unroll
    for (int o = 0; o < 3; ++o)
#pragma unroll
        for (int c = 0; c < 3; ++c)
            Wo[o * 3 + c] = comb_w[o * 6 + off + c];

    // Double-buffered line of hn (float4 for b128 LDS access), zero halo
    __shared__ float4 lds[2][S + 2];
    if (t < 2) {
        const int e = t * (S + 1);
        lds[0][e] = make_float4(0.f, 0.f, 0.f, 0.f);
        lds[1][e] = make_float4(0.f, 0.f, 0.f, 0.f);
    }

    // Global index of (b, c=0, step s, pos t); channel stride = HW
    int pos, stride;
    if (!isCol) { pos = b * IMG + t;     stride = S; } // x[b,c,s,t]
    else        { pos = b * IMG + t * S; stride = 1; } // x[b,c,t,s]

    float h0 = 0.f, h1 = 0.f, h2 = 0.f;
    float xa = x[pos], xb = x[pos + HW], xc = x[pos + 2 * HW];

#pragma unroll 2
    for (int s = 0; s < S; ++s) {
        const int nxt = pos + stride;
        float na = 0.f, nb = 0.f, nc = 0.f;
        if (s + 1 < S) {            // prefetch next step's input (uniform branch)
            na = x[nxt];
            nb = x[nxt + HW];
            nc = x[nxt + 2 * HW];
        }

        // ---- GRU cell (PyTorch gate order r,z,n) ----
        float gi[9], gh[9];
#pragma unroll
        for (int j = 0; j < 9; ++j) {
            gi[j] = fmaf(Wih[j * 3 + 2], xc,
                    fmaf(Wih[j * 3 + 1], xb,
                    fmaf(Wih[j * 3 + 0], xa, Bih[j])));
            gh[j] = fmaf(Whh[j * 3 + 2], h2,
                    fmaf(Whh[j * 3 + 1], h1,
                    fmaf(Whh[j * 3 + 0], h0, Bhh[j])));
        }
        const float r0 = fsig(gi[0] + gh[0]);
        const float r1 = fsig(gi[1] + gh[1]);
        const float r2 = fsig(gi[2] + gh[2]);
        const float z0 = fsig(gi[3] + gh[3]);
        const float z1 = fsig(gi[4] + gh[4]);
        const float z2 = fsig(gi[5] + gh[5]);
        const float n0 = ftanh(fmaf(r0, gh[6], gi[6]));
        const float n1 = ftanh(fmaf(r1, gh[7], gi[7]));
        const float n2 = ftanh(fmaf(r2, gh[8], gi[8]));
        const float c0 = fmaf(z0, h0 - n0, n0);  // (1-z)*n + z*h
        const float c1 = fmaf(z1, h1 - n1, n1);
        const float c2 = fmaf(z2, h2 - n2, n2);

        // ---- fold this direction's combine slice, push to global (no wait) ----
        const float o0 = fmaf(Wo[2], c2, fmaf(Wo[1], c1, Wo[0] * c0));
        const float o1 = fmaf(Wo[5], c2, fmaf(Wo[4], c1, Wo[3] * c0));
        const float o2 = fmaf(Wo[8], c2, fmaf(Wo[7], c1, Wo[6] * c0));
        if (ATOMIC) {
            unsafeAtomicAdd(&dst[pos],          o0);
            unsafeAtomicAdd(&dst[pos + HW],     o1);
            unsafeAtomicAdd(&dst[pos + 2 * HW], o2);
        } else {
            dst[pos]          = o0;
            dst[pos + HW]     = o1;
            dst[pos + 2 * HW] = o2;
        }

        // ---- exchange hn along the line (LDS only) ----
        const int buf = s & 1;
        lds[buf][t + 1] = make_float4(c0, c1, c2, 0.f);
        line_barrier();

        // ---- conv1d(k=3, pad=1) + tanh -> next hidden ----
        float a0 = Cb[0], a1 = Cb[1], a2 = Cb[2];
#pragma unroll
        for (int k = 0; k < 3; ++k) {
            const float4 v = lds[buf][t + k];
            a0 = fmaf(Cw[0 + 0 * 3 + k], v.x, fmaf(Cw[0 + 1 * 3 + k], v.y, fmaf(Cw[0 + 2 * 3 + k], v.z, a0)));
            a1 = fmaf(Cw[9 + 0 * 3 + k], v.x, fmaf(Cw[9 + 1 * 3 + k], v.y, fmaf(Cw[9 + 2 * 3 + k], v.z, a1)));
            a2 = fmaf(Cw[18 + 0 * 3 + k], v.x, fmaf(Cw[18 + 1 * 3 + k], v.y, fmaf(Cw[18 + 2 * 3 + k], v.z, a2)));
        }
        h0 = ftanh(a0); h1 = ftanh(a1); h2 = ftanh(a2);

        pos = nxt; xa = na; xb = nb; xc = nc;
    }
}

// ADDWS=1: out = sigmoid(out + ws + b[c]); ADDWS=0: out = sigmoid(out + b[c])
template <int ADDWS>
__global__ __launch_bounds__(256) void csrn_finish(
    float* __restrict__ out, const float* __restrict__ ws,
    const float* __restrict__ comb_b, int n4)
{
    const float b0 = comb_b[0], b1 = comb_b[1], b2 = comb_b[2];
    float4* o4 = reinterpret_cast<float4*>(out);
    const float4* w4 = reinterpret_cast<const float4*>(ws);
    for (int i = blockIdx.x * blockDim.x + threadIdx.x; i < n4;
         i += gridDim.x * blockDim.x) {
        float4 v = o4[i];
        if (ADDWS) {
            const float4 w = w4[i];
            v.x += w.x; v.y += w.y; v.z += w.z; v.w += w.w;
        }
        const int o = (i >> 16) % 3;           // elem index = 4i; HW = 2^18
        const float bb = (o == 0) ? b0 : ((o == 1) ? b1 : b2);
        v.x = fsig(v.x + bb);
        v.y = fsig(v.y + bb);
        v.z = fsig(v.z + bb);
        v.w = fsig(v.w + bb);
        o4[i] = v;
    }
}

extern "C" void kernel_launch(void* const* d_in, const int* in_sizes, int n_in,
                              void* d_out, int out_size, void* d_ws, size_t ws_size,
                              hipStream_t stream)
{
    const float* x      = (const float*)d_in[0];
    const float* wih_r  = (const float*)d_in[1];
    const float* whh_r  = (const float*)d_in[2];
    const float* bih_r  = (const float*)d_in[3];
    const float* bhh_r  = (const float*)d_in[4];
    const float* cw_r   = (const float*)d_in[5];
    const float* cb_r   = (const float*)d_in[6];
    const float* wih_c  = (const float*)d_in[7];
    const float* whh_c  = (const float*)d_in[8];
    const float* bih_c  = (const float*)d_in[9];
    const float* bhh_c  = (const float*)d_in[10];
    const float* cw_c   = (const float*)d_in[11];
    const float* cb_c   = (const float*)d_in[12];
    const float* comb_w = (const float*)d_in[13];
    const float* comb_b = (const float*)d_in[14];
    float* out = (float*)d_out;
    float* ws  = (float*)d_ws;

    const size_t need = (size_t)NB * IMG * sizeof(float);  // 100.7 MB
    const int n4 = out_size / 4;

    if (ws_size >= need) {
        // Plain-store path: rows -> out, cols -> ws; no atomics, no memset.
        // Every element of both buffers is written by exactly one thread-step.
        csrn_scan<0><<<dim3(2 * NB), dim3(S), 0, stream>>>(
            x, wih_r, whh_r, bih_r, bhh_r, cw_r, cb_r,
            wih_c, whh_c, bih_c, bhh_c, cw_c, cb_c, comb_w, out, ws);
        csrn_finish<1><<<dim3(4096), dim3(256), 0, stream>>>(out, ws, comb_b, n4);
    } else {
        // Fallback: both directions atomically accumulate into zeroed out.
        hipMemsetAsync(d_out, 0, (size_t)out_size * sizeof(float), stream);
        csrn_scan<1><<<dim3(2 * NB), dim3(S), 0, stream>>>(
            x, wih_r, whh_r, bih_r, bhh_r, cw_r, cb_r,
            wih_c, whh_c, bih_c, bhh_c, cw_c, cb_c, comb_w, out, out);
        csrn_finish<0><<<dim3(4096), dim3(256), 0, stream>>>(out, nullptr, comb_b, n4);
    }
}

// Round 5
// 772.934 us; speedup vs baseline: 2.2172x; 1.3065x over previous
//
#include <hip/hip_runtime.h>

#define NB 32              // batch
#define S  512             // H == W == scan length == line length
#define HW (512 * 512)
#define IMG (3 * HW)       // floats per image (C=3)
#define T  256             // scan threads; thread t owns line positions 2t, 2t+1

__device__ __forceinline__ float fsig(float v) {
    return __builtin_amdgcn_rcpf(1.0f + __expf(-v));
}
__device__ __forceinline__ float ftanh(float v) {
    // tanh(x) = 1 - 2/(1+exp(2x)); saturates correctly at +-inf
    return fmaf(-2.0f, __builtin_amdgcn_rcpf(1.0f + __expf(2.0f * v)), 1.0f);
}

// Barrier draining only LDS ops (lgkmcnt), NOT vmcnt: global stores and
// prefetch loads stay in flight across steps (round-2 fix, 1714->970 us).
__device__ __forceinline__ void line_barrier() {
    asm volatile("s_waitcnt lgkmcnt(0)" ::: "memory");
    __builtin_amdgcn_s_barrier();
    asm volatile("" ::: "memory");
}

// GRU cell for one position (PyTorch gate order r,z,n), C=3.
#define GRU3(XA, XB, XC, H0, H1, H2, C0, C1, C2)                               \
    {                                                                          \
        float gi[9], gh[9];                                                    \
        _Pragma("unroll")                                                      \
        for (int j = 0; j < 9; ++j) {                                          \
            gi[j] = fmaf(Wih[j * 3 + 2], (XC),                                 \
                    fmaf(Wih[j * 3 + 1], (XB),                                 \
                    fmaf(Wih[j * 3 + 0], (XA), Bih[j])));                      \
            gh[j] = fmaf(Whh[j * 3 + 2], (H2),                                 \
                    fmaf(Whh[j * 3 + 1], (H1),                                 \
                    fmaf(Whh[j * 3 + 0], (H0), Bhh[j])));                      \
        }                                                                      \
        const float r0 = fsig(gi[0] + gh[0]);                                  \
        const float r1 = fsig(gi[1] + gh[1]);                                  \
        const float r2 = fsig(gi[2] + gh[2]);                                  \
        const float z0 = fsig(gi[3] + gh[3]);                                  \
        const float z1 = fsig(gi[4] + gh[4]);                                  \
        const float z2 = fsig(gi[5] + gh[5]);                                  \
        const float q0 = ftanh(fmaf(r0, gh[6], gi[6]));                        \
        const float q1 = ftanh(fmaf(r1, gh[7], gi[7]));                        \
        const float q2 = ftanh(fmaf(r2, gh[8], gi[8]));                        \
        (C0) = fmaf(z0, (H0) - q0, q0);  /* (1-z)*n + z*h */                   \
        (C1) = fmaf(z1, (H1) - q1, q1);                                        \
        (C2) = fmaf(z2, (H2) - q2, q2);                                        \
    }

// conv accumulate for one output position given 3 input triples (k=0,1,2)
#define CONV3(V0X, V0Y, V0Z, V1X, V1Y, V1Z, V2X, V2Y, V2Z, H0, H1, H2)         \
    {                                                                          \
        float a0 = Cb[0], a1 = Cb[1], a2 = Cb[2];                              \
        a0 = fmaf(Cw[0], (V0X), fmaf(Cw[3], (V0Y), fmaf(Cw[6], (V0Z), a0)));   \
        a0 = fmaf(Cw[1], (V1X), fmaf(Cw[4], (V1Y), fmaf(Cw[7], (V1Z), a0)));   \
        a0 = fmaf(Cw[2], (V2X), fmaf(Cw[5], (V2Y), fmaf(Cw[8], (V2Z), a0)));   \
        a1 = fmaf(Cw[9],  (V0X), fmaf(Cw[12], (V0Y), fmaf(Cw[15], (V0Z), a1)));\
        a1 = fmaf(Cw[10], (V1X), fmaf(Cw[13], (V1Y), fmaf(Cw[16], (V1Z), a1)));\
        a1 = fmaf(Cw[11], (V2X), fmaf(Cw[14], (V2Y), fmaf(Cw[17], (V2Z), a1)));\
        a2 = fmaf(Cw[18], (V0X), fmaf(Cw[21], (V0Y), fmaf(Cw[24], (V0Z), a2)));\
        a2 = fmaf(Cw[19], (V1X), fmaf(Cw[22], (V1Y), fmaf(Cw[25], (V1Z), a2)));\
        a2 = fmaf(Cw[20], (V1X) * 0.f + (V2X), fmaf(Cw[23], (V2Y), fmaf(Cw[26], (V2Z), a2)));\
        (H0) = ftanh(a0); (H1) = ftanh(a1); (H2) = ftanh(a2);                  \
    }

// One scan line: thread t owns positions p0=2t, p1=2t+1.
// ISCOL=0: x[c][s][p], store ctx to dst[c][s][p]     (row scan, s = h)
// ISCOL=1: x[c][p][s], store ctx to dst[c][s][p]     (col scan, s = w; dst is
//          the TRANSPOSED ws layout [c][w][h] so stores stay coalesced)
// ATOMIC=1 fallback: fold combine slice (wo) and unsafeAtomicAdd into the
//          canonical [c][h][w] pixel layout.
template <int ISCOL, int ATOMIC>
__device__ __forceinline__ void scan_body(
    const float* __restrict__ xb,   // x + b*IMG
    float* __restrict__ dst,        // destination + b*IMG
    const float* __restrict__ wih, const float* __restrict__ whh,
    const float* __restrict__ bih, const float* __restrict__ bhh,
    const float* __restrict__ cw,  const float* __restrict__ cb,
    const float* __restrict__ wo,  // comb_w + (ISCOL?3:0), row-stride 6
    int t,
    float4 (*ldsA)[T + 1],          // even positions: cA(2t) at [t], halo [T]
    float4 (*ldsB)[T + 1])          // odd positions: cB(2t+1) at [t+1], halo [0]
{
    float Wih[27], Whh[27], Cw[27], Bih[9], Bhh[9], Cb[3];
#pragma unroll
    for (int i = 0; i < 27; ++i) { Wih[i] = wih[i]; Whh[i] = whh[i]; Cw[i] = cw[i]; }
#pragma unroll
    for (int i = 0; i < 9; ++i) { Bih[i] = bih[i]; Bhh[i] = bhh[i]; }
#pragma unroll
    for (int i = 0; i < 3; ++i) Cb[i] = cb[i];
    float Wo[9];
    if (ATOMIC) {
#pragma unroll
        for (int o = 0; o < 3; ++o)
#pragma unroll
            for (int c = 0; c < 3; ++c) Wo[o * 3 + c] = wo[o * 6 + c];
    }

    if (t < 2) {   // zero halos (disjoint from per-step slots; no race)
        ldsA[t][T] = make_float4(0.f, 0.f, 0.f, 0.f);
        ldsB[t][0] = make_float4(0.f, 0.f, 0.f, 0.f);
    }

    const int p0 = 2 * t;
    // hidden state, per position j in {0,1}, channels 0..2
    float h00 = 0.f, h01 = 0.f, h02 = 0.f, h10 = 0.f, h11 = 0.f, h12 = 0.f;

    // current x (step 0)
    float x00, x01, x02, x10, x11, x12;
    if (!ISCOL) {
        const float2 v0 = *(const float2*)&xb[0 * HW + p0];
        const float2 v1 = *(const float2*)&xb[1 * HW + p0];
        const float2 v2 = *(const float2*)&xb[2 * HW + p0];
        x00 = v0.x; x10 = v0.y; x01 = v1.x; x11 = v1.y; x02 = v2.x; x12 = v2.y;
    } else {
        x00 = xb[0 * HW + p0 * S];       x10 = xb[0 * HW + (p0 + 1) * S];
        x01 = xb[1 * HW + p0 * S];       x11 = xb[1 * HW + (p0 + 1) * S];
        x02 = xb[2 * HW + p0 * S];       x12 = xb[2 * HW + (p0 + 1) * S];
    }

#pragma unroll 2
    for (int s = 0; s < S; ++s) {
        // ---- prefetch next step's x (stays in flight past the barrier) ----
        float n00 = 0.f, n01 = 0.f, n02 = 0.f, n10 = 0.f, n11 = 0.f, n12 = 0.f;
        if (s + 1 < S) {
            if (!ISCOL) {
                const float2 v0 = *(const float2*)&xb[0 * HW + (s + 1) * S + p0];
                const float2 v1 = *(const float2*)&xb[1 * HW + (s + 1) * S + p0];
                const float2 v2 = *(const float2*)&xb[2 * HW + (s + 1) * S + p0];
                n00 = v0.x; n10 = v0.y; n01 = v1.x; n11 = v1.y; n02 = v2.x; n12 = v2.y;
            } else {
                n00 = xb[0 * HW + p0 * S + s + 1];  n10 = xb[0 * HW + (p0 + 1) * S + s + 1];
                n01 = xb[1 * HW + p0 * S + s + 1];  n11 = xb[1 * HW + (p0 + 1) * S + s + 1];
                n02 = xb[2 * HW + p0 * S + s + 1];  n12 = xb[2 * HW + (p0 + 1) * S + s + 1];
            }
        }

        // ---- GRU for both positions (independent -> ILP hides trans lat) ----
        float cA0, cA1, cA2, cB0, cB1, cB2;
        GRU3(x00, x01, x02, h00, h01, h02, cA0, cA1, cA2);
        GRU3(x10, x11, x12, h10, h11, h12, cB0, cB1, cB2);

        // ---- push ctx to global early (no wait in this kernel) ----
        if (!ATOMIC) {
            *(float2*)&dst[0 * HW + s * S + p0] = make_float2(cA0, cB0);
            *(float2*)&dst[1 * HW + s * S + p0] = make_float2(cA1, cB1);
            *(float2*)&dst[2 * HW + s * S + p0] = make_float2(cA2, cB2);
        } else {
            const int q0 = ISCOL ? (p0 * S + s) : (s * S + p0);
            const int q1 = ISCOL ? ((p0 + 1) * S + s) : (s * S + p0 + 1);
            unsafeAtomicAdd(&dst[0 * HW + q0], fmaf(Wo[2], cA2, fmaf(Wo[1], cA1, Wo[0] * cA0)));
            unsafeAtomicAdd(&dst[1 * HW + q0], fmaf(Wo[5], cA2, fmaf(Wo[4], cA1, Wo[3] * cA0)));
            unsafeAtomicAdd(&dst[2 * HW + q0], fmaf(Wo[8], cA2, fmaf(Wo[7], cA1, Wo[6] * cA0)));
            unsafeAtomicAdd(&dst[0 * HW + q1], fmaf(Wo[2], cB2, fmaf(Wo[1], cB1, Wo[0] * cB0)));
            unsafeAtomicAdd(&dst[1 * HW + q1], fmaf(Wo[5], cB2, fmaf(Wo[4], cB1, Wo[3] * cB0)));
            unsafeAtomicAdd(&dst[2 * HW + q1], fmaf(Wo[8], cB2, fmaf(Wo[7], cB1, Wo[6] * cB0)));
        }

        // ---- neighbor exchange: 2 writes + 2 reads per thread ----
        const int buf = s & 1;
        ldsA[buf][t]     = make_float4(cA0, cA1, cA2, 0.f);
        ldsB[buf][t + 1] = make_float4(cB0, cB1, cB2, 0.f);
        line_barrier();
        const float4 L = ldsB[buf][t];       // c[2t-1] (zero halo at t=0)
        const float4 R = ldsA[buf][t + 1];   // c[2t+2] (zero halo at t=T-1)

        // ---- conv1d(k=3,pad=1) + tanh -> next hidden ----
        // pos 2t  : inputs (L, cA, cB)
        CONV3(L.x, L.y, L.z, cA0, cA1, cA2, cB0, cB1, cB2, h00, h01, h02);
        // pos 2t+1: inputs (cA, cB, R)
        CONV3(cA0, cA1, cA2, cB0, cB1, cB2, R.x, R.y, R.z, h10, h11, h12);

        x00 = n00; x01 = n01; x02 = n02; x10 = n10; x11 = n11; x12 = n12;
    }
}

template <int ATOMIC>
__global__ __launch_bounds__(T) void csrn_scan(
    const float* __restrict__ x,
    const float* __restrict__ wih_r, const float* __restrict__ whh_r,
    const float* __restrict__ bih_r, const float* __restrict__ bhh_r,
    const float* __restrict__ cw_r,  const float* __restrict__ cb_r,
    const float* __restrict__ wih_c, const float* __restrict__ whh_c,
    const float* __restrict__ bih_c, const float* __restrict__ bhh_c,
    const float* __restrict__ cw_c,  const float* __restrict__ cb_c,
    const float* __restrict__ comb_w,
    float* __restrict__ dstRow, float* __restrict__ dstCol)
{
    __shared__ float4 ldsA[2][T + 1];
    __shared__ float4 ldsB[2][T + 1];
    const int  t     = threadIdx.x;
    const bool isCol = (blockIdx.x >= NB);
    const int  b     = blockIdx.x & (NB - 1);
    const float* xb  = x + b * IMG;
    if (!isCol)
        scan_body<0, ATOMIC>(xb, dstRow + b * IMG, wih_r, whh_r, bih_r, bhh_r,
                             cw_r, cb_r, comb_w, t, ldsA, ldsB);
    else
        scan_body<1, ATOMIC>(xb, dstCol + b * IMG, wih_c, whh_c, bih_c, bhh_c,
                             cw_c, cb_c, comb_w + 3, t, ldsA, ldsB);
}

// Plain path: out holds ctx_above [b][c][h][w]; wsT holds ctx_left transposed
// [b][c][w][h]. Compute out = sigmoid(Wa·ctxA + Wl·ctxL + bias) in place.
__global__ __launch_bounds__(256) void csrn_combine(
    float* __restrict__ out, const float* __restrict__ wsT,
    const float* __restrict__ comb_w, const float* __restrict__ comb_b)
{
    const int i  = blockIdx.x * blockDim.x + threadIdx.x;  // [b][h][w4]
    const int w0 = (i & 127) << 2;
    const int h  = (i >> 7) & 511;
    const int b  = i >> 16;                                // 512*128 = 2^16
    float W[18], bb[3];
#pragma unroll
    for (int k = 0; k < 18; ++k) W[k] = comb_w[k];
#pragma unroll
    for (int k = 0; k < 3; ++k) bb[k] = comb_b[k];

    float* A        = out + b * IMG;
    const float* Lb = wsT + b * IMG;
    const float4 a0 = *(const float4*)&A[0 * HW + h * S + w0];
    const float4 a1 = *(const float4*)&A[1 * HW + h * S + w0];
    const float4 a2 = *(const float4*)&A[2 * HW + h * S + w0];
    float l0[4], l1[4], l2[4];
#pragma unroll
    for (int j = 0; j < 4; ++j) {
        l0[j] = Lb[0 * HW + (w0 + j) * S + h];
        l1[j] = Lb[1 * HW + (w0 + j) * S + h];
        l2[j] = Lb[2 * HW + (w0 + j) * S + h];
    }
    const float av0[4] = {a0.x, a0.y, a0.z, a0.w};
    const float av1[4] = {a1.x, a1.y, a1.z, a1.w};
    const float av2[4] = {a2.x, a2.y, a2.z, a2.w};
#pragma unroll
    for (int o = 0; o < 3; ++o) {
        float4 r;
        float* rp = &r.x;
#pragma unroll
        for (int j = 0; j < 4; ++j) {
            float v = bb[o];
            v = fmaf(W[o * 6 + 0], av0[j], v);
            v = fmaf(W[o * 6 + 1], av1[j], v);
            v = fmaf(W[o * 6 + 2], av2[j], v);
            v = fmaf(W[o * 6 + 3], l0[j], v);
            v = fmaf(W[o * 6 + 4], l1[j], v);
            v = fmaf(W[o * 6 + 5], l2[j], v);
            rp[j] = fsig(v);
        }
        *(float4*)&A[o * HW + h * S + w0] = r;
    }
}

// Fallback finish: out = sigmoid(out + bias[c])
__global__ __launch_bounds__(256) void csrn_bias_sig(
    float* __restrict__ out, const float* __restrict__ comb_b, int n4)
{
    const float b0 = comb_b[0], b1 = comb_b[1], b2 = comb_b[2];
    float4* o4 = reinterpret_cast<float4*>(out);
    for (int i = blockIdx.x * blockDim.x + threadIdx.x; i < n4;
         i += gridDim.x * blockDim.x) {
        float4 v = o4[i];
        const int o = (i >> 16) % 3;
        const float bb = (o == 0) ? b0 : ((o == 1) ? b1 : b2);
        v.x = fsig(v.x + bb); v.y = fsig(v.y + bb);
        v.z = fsig(v.z + bb); v.w = fsig(v.w + bb);
        o4[i] = v;
    }
}

extern "C" void kernel_launch(void* const* d_in, const int* in_sizes, int n_in,
                              void* d_out, int out_size, void* d_ws, size_t ws_size,
                              hipStream_t stream)
{
    const float* x      = (const float*)d_in[0];
    const float* wih_r  = (const float*)d_in[1];
    const float* whh_r  = (const float*)d_in[2];
    const float* bih_r  = (const float*)d_in[3];
    const float* bhh_r  = (const float*)d_in[4];
    const float* cw_r   = (const float*)d_in[5];
    const float* cb_r   = (const float*)d_in[6];
    const float* wih_c  = (const float*)d_in[7];
    const float* whh_c  = (const float*)d_in[8];
    const float* bih_c  = (const float*)d_in[9];
    const float* bhh_c  = (const float*)d_in[10];
    const float* cw_c   = (const float*)d_in[11];
    const float* cb_c   = (const float*)d_in[12];
    const float* comb_w = (const float*)d_in[13];
    const float* comb_b = (const float*)d_in[14];
    float* out = (float*)d_out;
    float* ws  = (float*)d_ws;

    const size_t need = (size_t)NB * IMG * sizeof(float);  // 100.7 MB

    if (ws_size >= need) {
        // rows -> out (ctx_above, [b][c][h][w]); cols -> ws (ctx_left
        // TRANSPOSED, [b][c][w][h]) so all scan stores are coalesced float2.
        csrn_scan<0><<<dim3(2 * NB), dim3(T), 0, stream>>>(
            x, wih_r, whh_r, bih_r, bhh_r, cw_r, cb_r,
            wih_c, whh_c, bih_c, bhh_c, cw_c, cb_c, comb_w, out, ws);
        csrn_combine<<<dim3(NB * 512 * 128 / 256), dim3(256), 0, stream>>>(
            out, ws, comb_w, comb_b);
    } else {
        hipMemsetAsync(d_out, 0, (size_t)out_size * sizeof(float), stream);
        csrn_scan<1><<<dim3(2 * NB), dim3(T), 0, stream>>>(
            x, wih_r, whh_r, bih_r, bhh_r, cw_r, cb_r,
            wih_c, whh_c, bih_c, bhh_c, cw_c, cb_c, comb_w, out, out);
        csrn_bias_sig<<<dim3(4096), dim3(256), 0, stream>>>(out, comb_b, out_size / 4);
    }
}

// Round 6
// 641.577 us; speedup vs baseline: 2.6711x; 1.2047x over previous
//
#include <hip/hip_runtime.h>

#define NB 32              // batch
#define S  512             // H == W == scan length == line length
#define HW (512 * 512)
#define IMG (3 * HW)       // floats per image (C=3)
#define T  256             // scan threads; thread t owns line positions 2t, 2t+1

__device__ __forceinline__ float fsig(float v) {
    return __builtin_amdgcn_rcpf(1.0f + __expf(-v));
}
__device__ __forceinline__ float ftanh(float v) {
    // tanh(x) = 1 - 2/(1+exp(2x)); saturates correctly at +-inf
    return fmaf(-2.0f, __builtin_amdgcn_rcpf(1.0f + __expf(2.0f * v)), 1.0f);
}

// Barrier draining only LDS ops (lgkmcnt), NOT vmcnt: global stores and
// prefetch loads stay in flight across steps (round-2 fix, 1714->970 us).
__device__ __forceinline__ void line_barrier() {
    asm volatile("s_waitcnt lgkmcnt(0)" ::: "memory");
    __builtin_amdgcn_s_barrier();
    asm volatile("" ::: "memory");
}

// gi = W_ih * x + b_ih for one position (independent of h -> pipelined ahead)
__device__ __forceinline__ void gi_compute(const float* __restrict__ Wih,
                                           const float* __restrict__ Bih,
                                           float xa, float xb, float xc,
                                           float* __restrict__ gi) {
#pragma unroll
    for (int j = 0; j < 9; ++j)
        gi[j] = fmaf(Wih[j * 3 + 2], xc,
                fmaf(Wih[j * 3 + 1], xb,
                fmaf(Wih[j * 3 + 0], xa, Bih[j])));
}

// GRU gates given precomputed gi (PyTorch gate order r,z,n), C=3
__device__ __forceinline__ void gru_gates(const float* __restrict__ Whh,
                                          const float* __restrict__ Bhh,
                                          const float* __restrict__ gi,
                                          float h0, float h1, float h2,
                                          float& c0, float& c1, float& c2) {
    float gh[9];
#pragma unroll
    for (int j = 0; j < 9; ++j)
        gh[j] = fmaf(Whh[j * 3 + 2], h2,
                fmaf(Whh[j * 3 + 1], h1,
                fmaf(Whh[j * 3 + 0], h0, Bhh[j])));
    const float r0 = fsig(gi[0] + gh[0]);
    const float r1 = fsig(gi[1] + gh[1]);
    const float r2 = fsig(gi[2] + gh[2]);
    const float z0 = fsig(gi[3] + gh[3]);
    const float z1 = fsig(gi[4] + gh[4]);
    const float z2 = fsig(gi[5] + gh[5]);
    const float q0 = ftanh(fmaf(r0, gh[6], gi[6]));
    const float q1 = ftanh(fmaf(r1, gh[7], gi[7]));
    const float q2 = ftanh(fmaf(r2, gh[8], gi[8]));
    c0 = fmaf(z0, h0 - q0, q0);  // (1-z)*n + z*h
    c1 = fmaf(z1, h1 - q1, q1);
    c2 = fmaf(z2, h2 - q2, q2);
}

// conv partials using only OWN registers (pos 2t: taps k=1(cA),k=2(cB);
// pos 2t+1: taps k=0(cA),k=1(cB)). Runs BEFORE the barrier.
__device__ __forceinline__ void conv_own(const float* __restrict__ Cw,
                                         const float* __restrict__ Cb,
                                         float cA0, float cA1, float cA2,
                                         float cB0, float cB1, float cB2,
                                         float* __restrict__ pA,
                                         float* __restrict__ pB) {
#pragma unroll
    for (int o = 0; o < 3; ++o) {
        float v = Cb[o];
        v = fmaf(Cw[o * 9 + 1], cA0, v);
        v = fmaf(Cw[o * 9 + 4], cA1, v);
        v = fmaf(Cw[o * 9 + 7], cA2, v);
        v = fmaf(Cw[o * 9 + 2], cB0, v);
        v = fmaf(Cw[o * 9 + 5], cB1, v);
        v = fmaf(Cw[o * 9 + 8], cB2, v);
        pA[o] = v;
        float u = Cb[o];
        u = fmaf(Cw[o * 9 + 0], cA0, u);
        u = fmaf(Cw[o * 9 + 3], cA1, u);
        u = fmaf(Cw[o * 9 + 6], cA2, u);
        u = fmaf(Cw[o * 9 + 1], cB0, u);
        u = fmaf(Cw[o * 9 + 4], cB1, u);
        u = fmaf(Cw[o * 9 + 7], cB2, u);
        pB[o] = u;
    }
}

// finish conv with neighbor taps (L for pos 2t k=0, R for pos 2t+1 k=2) + tanh
__device__ __forceinline__ void conv_fin(const float* __restrict__ Cw,
                                         const float* __restrict__ pA,
                                         const float* __restrict__ pB,
                                         float L0, float L1, float L2,
                                         float R0, float R1, float R2,
                                         float& hA0, float& hA1, float& hA2,
                                         float& hB0, float& hB1, float& hB2) {
    float a0 = fmaf(Cw[0 * 9 + 0], L0, fmaf(Cw[0 * 9 + 3], L1, fmaf(Cw[0 * 9 + 6], L2, pA[0])));
    float a1 = fmaf(Cw[1 * 9 + 0], L0, fmaf(Cw[1 * 9 + 3], L1, fmaf(Cw[1 * 9 + 6], L2, pA[1])));
    float a2 = fmaf(Cw[2 * 9 + 0], L0, fmaf(Cw[2 * 9 + 3], L1, fmaf(Cw[2 * 9 + 6], L2, pA[2])));
    float b0 = fmaf(Cw[0 * 9 + 2], R0, fmaf(Cw[0 * 9 + 5], R1, fmaf(Cw[0 * 9 + 8], R2, pB[0])));
    float b1 = fmaf(Cw[1 * 9 + 2], R0, fmaf(Cw[1 * 9 + 5], R1, fmaf(Cw[1 * 9 + 8], R2, pB[1])));
    float b2 = fmaf(Cw[2 * 9 + 2], R0, fmaf(Cw[2 * 9 + 5], R1, fmaf(Cw[2 * 9 + 8], R2, pB[2])));
    hA0 = ftanh(a0); hA1 = ftanh(a1); hA2 = ftanh(a2);
    hB0 = ftanh(b0); hB1 = ftanh(b1); hB2 = ftanh(b2);
}

// load x for both positions (A=2t, B=2t+1), all 3 channels, at line-step idx
template <int ISCOL>
__device__ __forceinline__ void load6(const float* __restrict__ xb, int idx, int p0,
                                      float& a0, float& a1, float& a2,
                                      float& b0, float& b1, float& b2) {
    if (!ISCOL) {
        const float2 v0 = *(const float2*)&xb[0 * HW + idx * S + p0];
        const float2 v1 = *(const float2*)&xb[1 * HW + idx * S + p0];
        const float2 v2 = *(const float2*)&xb[2 * HW + idx * S + p0];
        a0 = v0.x; b0 = v0.y; a1 = v1.x; b1 = v1.y; a2 = v2.x; b2 = v2.y;
    } else {
        a0 = xb[0 * HW + p0 * S + idx];       b0 = xb[0 * HW + (p0 + 1) * S + idx];
        a1 = xb[1 * HW + p0 * S + idx];       b1 = xb[1 * HW + (p0 + 1) * S + idx];
        a2 = xb[2 * HW + p0 * S + idx];       b2 = xb[2 * HW + (p0 + 1) * S + idx];
    }
}

// One scan line: thread t owns positions 2t, 2t+1.
// ISCOL=0: x[c][s][p], ctx -> dst[c][s][p]            (row scan, s=h)
// ISCOL=1: x[c][p][s], ctx -> dst[c][s][p] (=ws [c][w][h], coalesced stores)
// ATOMIC=1 fallback: fold combine slice and atomically add into [c][h][w].
template <int ISCOL, int ATOMIC>
__device__ __forceinline__ void scan_body(
    const float* __restrict__ xb, float* __restrict__ dst,
    const float* __restrict__ wih, const float* __restrict__ whh,
    const float* __restrict__ bih, const float* __restrict__ bhh,
    const float* __restrict__ cw,  const float* __restrict__ cb,
    const float* __restrict__ wo, int t,
    float4 (*ldsA)[T + 1], float4 (*ldsB)[T + 1])
{
    float Wih[27], Whh[27], Cw[27], Bih[9], Bhh[9], Cb[3];
#pragma unroll
    for (int i = 0; i < 27; ++i) { Wih[i] = wih[i]; Whh[i] = whh[i]; Cw[i] = cw[i]; }
#pragma unroll
    for (int i = 0; i < 9; ++i) { Bih[i] = bih[i]; Bhh[i] = bhh[i]; }
#pragma unroll
    for (int i = 0; i < 3; ++i) Cb[i] = cb[i];
    float Wo[9];
    if (ATOMIC) {
#pragma unroll
        for (int o = 0; o < 3; ++o)
#pragma unroll
            for (int c = 0; c < 3; ++c) Wo[o * 3 + c] = wo[o * 6 + c];
    }

    if (t < 2) {   // zero halos (disjoint from per-step slots)
        ldsA[t][T] = make_float4(0.f, 0.f, 0.f, 0.f);
        ldsB[t][0] = make_float4(0.f, 0.f, 0.f, 0.f);
    }

    const int p0 = 2 * t;
    float h00 = 0.f, h01 = 0.f, h02 = 0.f, h10 = 0.f, h11 = 0.f, h12 = 0.f;

    // ---- prologue: gi(0) from x(0); xn holds x(1) ----
    float giA[9], giB[9];
    {
        float a0, a1, a2, b0, b1, b2;
        load6<ISCOL>(xb, 0, p0, a0, a1, a2, b0, b1, b2);
        gi_compute(Wih, Bih, a0, a1, a2, giA);
        gi_compute(Wih, Bih, b0, b1, b2, giB);
    }
    float xn0, xn1, xn2, xn3, xn4, xn5;
    load6<ISCOL>(xb, 1, p0, xn0, xn1, xn2, xn3, xn4, xn5);

    for (int s = 0; s < S; ++s) {
        // ---- GRU gates from precomputed gi ----
        float cA0, cA1, cA2, cB0, cB1, cB2;
        gru_gates(Whh, Bhh, giA, h00, h01, h02, cA0, cA1, cA2);
        gru_gates(Whh, Bhh, giB, h10, h11, h12, cB0, cB1, cB2);

        // ---- LDS neighbor exchange write ----
        const int buf = s & 1;
        ldsA[buf][t]     = make_float4(cA0, cA1, cA2, 0.f);
        ldsB[buf][t + 1] = make_float4(cB0, cB1, cB2, 0.f);

        // ---- push ctx to global (fire-and-forget) ----
        if (!ATOMIC) {
            *(float2*)&dst[0 * HW + s * S + p0] = make_float2(cA0, cB0);
            *(float2*)&dst[1 * HW + s * S + p0] = make_float2(cA1, cB1);
            *(float2*)&dst[2 * HW + s * S + p0] = make_float2(cA2, cB2);
        } else {
            const int q0 = ISCOL ? (p0 * S + s) : (s * S + p0);
            const int q1 = ISCOL ? ((p0 + 1) * S + s) : (s * S + p0 + 1);
            unsafeAtomicAdd(&dst[0 * HW + q0], fmaf(Wo[2], cA2, fmaf(Wo[1], cA1, Wo[0] * cA0)));
            unsafeAtomicAdd(&dst[1 * HW + q0], fmaf(Wo[5], cA2, fmaf(Wo[4], cA1, Wo[3] * cA0)));
            unsafeAtomicAdd(&dst[2 * HW + q0], fmaf(Wo[8], cA2, fmaf(Wo[7], cA1, Wo[6] * cA0)));
            unsafeAtomicAdd(&dst[0 * HW + q1], fmaf(Wo[2], cB2, fmaf(Wo[1], cB1, Wo[0] * cB0)));
            unsafeAtomicAdd(&dst[1 * HW + q1], fmaf(Wo[5], cB2, fmaf(Wo[4], cB1, Wo[3] * cB0)));
            unsafeAtomicAdd(&dst[2 * HW + q1], fmaf(Wo[8], cB2, fmaf(Wo[7], cB1, Wo[6] * cB0)));
        }

        // ---- conv own-register taps BEFORE the barrier ----
        float pA[3], pB[3];
        conv_own(Cw, Cb, cA0, cA1, cA2, cB0, cB1, cB2, pA, pB);

        line_barrier();

        // ---- issue neighbor reads, fill their latency with gi(s+1) ----
        const float4 L = ldsB[buf][t];       // c[2t-1] (zero halo at t=0)
        const float4 R = ldsA[buf][t + 1];   // c[2t+2] (zero halo at t=T-1)

        gi_compute(Wih, Bih, xn0, xn1, xn2, giA);   // uses x(s+1)
        gi_compute(Wih, Bih, xn3, xn4, xn5, giB);

        // reload xn with x(s+2); consumed next iteration (full-step distance)
        load6<ISCOL>(xb, (s + 2 < S) ? (s + 2) : (S - 1), p0,
                     xn0, xn1, xn2, xn3, xn4, xn5);

        // ---- finish conv with L/R taps + tanh -> next hidden ----
        conv_fin(Cw, pA, pB, L.x, L.y, L.z, R.x, R.y, R.z,
                 h00, h01, h02, h10, h11, h12);
    }
}

template <int ATOMIC>
__global__ __launch_bounds__(T) void csrn_scan(
    const float* __restrict__ x,
    const float* __restrict__ wih_r, const float* __restrict__ whh_r,
    const float* __restrict__ bih_r, const float* __restrict__ bhh_r,
    const float* __restrict__ cw_r,  const float* __restrict__ cb_r,
    const float* __restrict__ wih_c, const float* __restrict__ whh_c,
    const float* __restrict__ bih_c, const float* __restrict__ bhh_c,
    const float* __restrict__ cw_c,  const float* __restrict__ cb_c,
    const float* __restrict__ comb_w,
    float* __restrict__ dstRow, float* __restrict__ dstCol)
{
    __shared__ float4 ldsA[2][T + 1];
    __shared__ float4 ldsB[2][T + 1];
    const int  t     = threadIdx.x;
    const bool isCol = (blockIdx.x >= NB);
    const int  b     = blockIdx.x & (NB - 1);
    const float* xb  = x + b * IMG;
    if (!isCol)
        scan_body<0, ATOMIC>(xb, dstRow + b * IMG, wih_r, whh_r, bih_r, bhh_r,
                             cw_r, cb_r, comb_w, t, ldsA, ldsB);
    else
        scan_body<1, ATOMIC>(xb, dstCol + b * IMG, wih_c, whh_c, bih_c, bhh_c,
                             cw_c, cb_c, comb_w + 3, t, ldsA, ldsB);
}

// Plain path: out = ctx_above [b][c][h][w]; wsT = ctx_left transposed
// [b][c][w][h]. 64x64 LDS tile transposes wsT so ALL global accesses are
// coalesced; stride-65 LDS rows are bank-conflict-free.
__global__ __launch_bounds__(256) void csrn_combine(
    float* __restrict__ out, const float* __restrict__ wsT,
    const float* __restrict__ comb_w, const float* __restrict__ comb_b)
{
    __shared__ float ldsT[3][64][65];
    const int tx = threadIdx.x;            // 0..63
    const int ty = threadIdx.y;            // 0..3
    const int bid = blockIdx.x;            // 32 b * 8 * 8
    const int b  = bid >> 6;
    const int th = ((bid >> 3) & 7) * 64;
    const int tw = (bid & 7) * 64;
    const float* Lb = wsT + b * IMG;
    float* A = out + b * IMG;

#pragma unroll 4
    for (int c = 0; c < 3; ++c)
        for (int r = 0; r < 16; ++r) {
            const int row = (r << 2) + ty;   // w-offset within tile
            ldsT[c][row][tx] = Lb[c * HW + (tw + row) * S + th + tx];
        }
    __syncthreads();

    float W[18], bb[3];
#pragma unroll
    for (int k = 0; k < 18; ++k) W[k] = comb_w[k];
#pragma unroll
    for (int k = 0; k < 3; ++k) bb[k] = comb_b[k];

    const int w = tw + tx;
#pragma unroll 4
    for (int r = 0; r < 16; ++r) {
        const int hr = (r << 2) + ty;
        const int h  = th + hr;
        const float a0 = A[0 * HW + h * S + w];
        const float a1 = A[1 * HW + h * S + w];
        const float a2 = A[2 * HW + h * S + w];
        const float l0 = ldsT[0][tx][hr];
        const float l1 = ldsT[1][tx][hr];
        const float l2 = ldsT[2][tx][hr];
#pragma unroll
        for (int o = 0; o < 3; ++o) {
            float v = bb[o];
            v = fmaf(W[o * 6 + 0], a0, v);
            v = fmaf(W[o * 6 + 1], a1, v);
            v = fmaf(W[o * 6 + 2], a2, v);
            v = fmaf(W[o * 6 + 3], l0, v);
            v = fmaf(W[o * 6 + 4], l1, v);
            v = fmaf(W[o * 6 + 5], l2, v);
            A[o * HW + h * S + w] = fsig(v);
        }
    }
}

// Fallback finish: out = sigmoid(out + bias[c])
__global__ __launch_bounds__(256) void csrn_bias_sig(
    float* __restrict__ out, const float* __restrict__ comb_b, int n4)
{
    const float b0 = comb_b[0], b1 = comb_b[1], b2 = comb_b[2];
    float4* o4 = reinterpret_cast<float4*>(out);
    for (int i = blockIdx.x * blockDim.x + threadIdx.x; i < n4;
         i += gridDim.x * blockDim.x) {
        float4 v = o4[i];
        const int o = (i >> 16) % 3;
        const float bb = (o == 0) ? b0 : ((o == 1) ? b1 : b2);
        v.x = fsig(v.x + bb); v.y = fsig(v.y + bb);
        v.z = fsig(v.z + bb); v.w = fsig(v.w + bb);
        o4[i] = v;
    }
}

extern "C" void kernel_launch(void* const* d_in, const int* in_sizes, int n_in,
                              void* d_out, int out_size, void* d_ws, size_t ws_size,
                              hipStream_t stream)
{
    const float* x      = (const float*)d_in[0];
    const float* wih_r  = (const float*)d_in[1];
    const float* whh_r  = (const float*)d_in[2];
    const float* bih_r  = (const float*)d_in[3];
    const float* bhh_r  = (const float*)d_in[4];
    const float* cw_r   = (const float*)d_in[5];
    const float* cb_r   = (const float*)d_in[6];
    const float* wih_c  = (const float*)d_in[7];
    const float* whh_c  = (const float*)d_in[8];
    const float* bih_c  = (const float*)d_in[9];
    const float* bhh_c  = (const float*)d_in[10];
    const float* cw_c   = (const float*)d_in[11];
    const float* cb_c   = (const float*)d_in[12];
    const float* comb_w = (const float*)d_in[13];
    const float* comb_b = (const float*)d_in[14];
    float* out = (float*)d_out;
    float* ws  = (float*)d_ws;

    const size_t need = (size_t)NB * IMG * sizeof(float);  // 100.7 MB

    if (ws_size >= need) {
        // rows -> out (ctx_above [b][c][h][w]); cols -> ws (ctx_left
        // TRANSPOSED [b][c][w][h]) so all scan stores are coalesced float2.
        csrn_scan<0><<<dim3(2 * NB), dim3(T), 0, stream>>>(
            x, wih_r, whh_r, bih_r, bhh_r, cw_r, cb_r,
            wih_c, whh_c, bih_c, bhh_c, cw_c, cb_c, comb_w, out, ws);
        csrn_combine<<<dim3(NB * 64), dim3(64, 4), 0, stream>>>(
            out, ws, comb_w, comb_b);
    } else {
        hipMemsetAsync(d_out, 0, (size_t)out_size * sizeof(float), stream);
        csrn_scan<1><<<dim3(2 * NB), dim3(T), 0, stream>>>(
            x, wih_r, whh_r, bih_r, bhh_r, cw_r, cb_r,
            wih_c, whh_c, bih_c, bhh_c, cw_c, cb_c, comb_w, out, out);
        csrn_bias_sig<<<dim3(4096), dim3(256), 0, stream>>>(out, comb_b, out_size / 4);
    }
}